// Round 1
// baseline (1550.084 us; speedup 1.0000x reference)
//
#include <hip/hip_runtime.h>
#include <hip/hip_bf16.h>
#include <cmath>

#define NROW 2048      // B*S
#define DMODEL 512
#define FIN 240
#define NHEAD 16
#define DHEAD 32
#define CHUNK 64
#define NCHUNK 16      // S / CHUNK
#define NLAYER 6
#define SEQ 1024

// phi(x) = elu(x) + 1
__device__ __forceinline__ float phi(float x) {
    return x > 0.f ? x + 1.f : expf(x);
}

// ---------------- LayerNorm (optionally fused residual add) ----------------
// one block per row, 256 threads; C <= 512
__global__ __launch_bounds__(256) void ln_kernel(
    const float* in, const float* res,
    const float* __restrict__ g, const float* __restrict__ b,
    float* out, int C) {
    int row = blockIdx.x;
    int tid = threadIdx.x;
    const float* xr = in + (size_t)row * C;
    const float* rr = res ? res + (size_t)row * C : nullptr;
    float vals[2];
    float sum = 0.f, sq = 0.f;
#pragma unroll
    for (int i = 0; i < 2; ++i) {
        int c = tid + i * 256;
        float v = 0.f;
        if (c < C) { v = xr[c]; if (rr) v += rr[c]; }
        vals[i] = v;
        sum += v; sq += v * v;
    }
#pragma unroll
    for (int off = 32; off > 0; off >>= 1) {
        sum += __shfl_xor(sum, off, 64);
        sq  += __shfl_xor(sq,  off, 64);
    }
    __shared__ float red[8];
    int wv = tid >> 6, ln = tid & 63;
    if (ln == 0) { red[wv] = sum; red[4 + wv] = sq; }
    __syncthreads();
    sum = red[0] + red[1] + red[2] + red[3];
    sq  = red[4] + red[5] + red[6] + red[7];
    float mean = sum / (float)C;
    float var  = sq / (float)C - mean * mean;
    float rstd = rsqrtf(var + 1e-5f);
#pragma unroll
    for (int i = 0; i < 2; ++i) {
        int c = tid + i * 256;
        if (c < C) out[(size_t)row * C + c] = (vals[i] - mean) * rstd * g[c] + b[c];
    }
}

// ---------------- fp32 tiled GEMM: C = A[M,K] * B[K,N] + bias, opt relu ----
// BM=BN=64, BK=32, 256 threads, 4x4 per thread
__global__ __launch_bounds__(256) void gemm_kernel(
    const float* __restrict__ A, const float* __restrict__ B,
    const float* __restrict__ bias, float* __restrict__ C,
    int M, int N, int K, int relu) {
    __shared__ float As[32][68];
    __shared__ float Bs[32][68];
    int tid = threadIdx.x;
    int bm = blockIdx.x * 64;
    int bn = blockIdx.y * 64;
    int tx = tid & 15, ty = tid >> 4;
    int row_a = tid >> 3;        // 0..31
    int kk_a  = (tid & 7) * 4;   // 0..28
    int col_b = (tid & 15) * 4;  // 0..60
    int kk_b  = tid >> 4;        // 0..15
    float acc[4][4] = {};
    for (int k0 = 0; k0 < K; k0 += 32) {
#pragma unroll
        for (int rrr = 0; rrr < 2; ++rrr) {
            int r = row_a + rrr * 32;
            float4 av = make_float4(0.f, 0.f, 0.f, 0.f);
            if (k0 + kk_a < K)
                av = *(const float4*)&A[(size_t)(bm + r) * K + k0 + kk_a];
            As[kk_a + 0][r] = av.x;
            As[kk_a + 1][r] = av.y;
            As[kk_a + 2][r] = av.z;
            As[kk_a + 3][r] = av.w;
        }
#pragma unroll
        for (int rrr = 0; rrr < 2; ++rrr) {
            int kk = kk_b + rrr * 16;
            float4 bv = make_float4(0.f, 0.f, 0.f, 0.f);
            if (k0 + kk < K)
                bv = *(const float4*)&B[(size_t)(k0 + kk) * N + bn + col_b];
            *(float4*)&Bs[kk][col_b] = bv;
        }
        __syncthreads();
#pragma unroll
        for (int kk = 0; kk < 32; ++kk) {
            float4 a4 = *(const float4*)&As[kk][ty * 4];
            float4 b4 = *(const float4*)&Bs[kk][tx * 4];
            float aa[4] = {a4.x, a4.y, a4.z, a4.w};
            float bb[4] = {b4.x, b4.y, b4.z, b4.w};
#pragma unroll
            for (int i = 0; i < 4; ++i)
#pragma unroll
                for (int j = 0; j < 4; ++j)
                    acc[i][j] = fmaf(aa[i], bb[j], acc[i][j]);
        }
        __syncthreads();
    }
#pragma unroll
    for (int i = 0; i < 4; ++i) {
        int r = bm + ty * 4 + i;
        float4 o;
        o.x = acc[i][0] + bias[bn + tx * 4 + 0];
        o.y = acc[i][1] + bias[bn + tx * 4 + 1];
        o.z = acc[i][2] + bias[bn + tx * 4 + 2];
        o.w = acc[i][3] + bias[bn + tx * 4 + 3];
        if (relu) {
            o.x = fmaxf(o.x, 0.f); o.y = fmaxf(o.y, 0.f);
            o.z = fmaxf(o.z, 0.f); o.w = fmaxf(o.w, 0.f);
        }
        *(float4*)&C[(size_t)r * N + bn + tx * 4] = o;
    }
}

// ---------------- attention phase A: per-chunk K^T V sums + K column sums --
// grid (NCHUNK, NHEAD, B), 256 threads
__global__ __launch_bounds__(256) void attn_sums_kernel(
    const float* __restrict__ k, const float* __restrict__ v,
    float* __restrict__ kvsum, float* __restrict__ ksum) {
    __shared__ float Ks[CHUNK][33];
    __shared__ float Vs[CHUNK][33];
    int c = blockIdx.x, hh = blockIdx.y, b = blockIdx.z;
    int tid = threadIdx.x;
    size_t base = ((size_t)(b * SEQ + c * CHUNK)) * DMODEL + hh * DHEAD;
#pragma unroll
    for (int i = 0; i < 8; ++i) {
        int s = (tid >> 5) + i * 8;
        int d = tid & 31;
        float kv_ = k[base + (size_t)s * DMODEL + d];
        Ks[s][d] = phi(kv_);
        Vs[s][d] = v[base + (size_t)s * DMODEL + d];
    }
    __syncthreads();
    int m = tid & 31;
    float acc[4] = {0.f, 0.f, 0.f, 0.f};
    for (int s = 0; s < CHUNK; ++s) {
        float vm = Vs[s][m];
#pragma unroll
        for (int i = 0; i < 4; ++i)
            acc[i] = fmaf(Ks[s][(tid >> 5) + 8 * i], vm, acc[i]);
    }
    size_t ob = ((size_t)((b * NHEAD + hh) * NCHUNK + c)) * (DHEAD * DHEAD);
#pragma unroll
    for (int i = 0; i < 4; ++i)
        kvsum[ob + (size_t)((tid >> 5) + 8 * i) * DHEAD + m] = acc[i];
    if (tid < 32) {
        float s_ = 0.f;
        for (int s = 0; s < CHUNK; ++s) s_ += Ks[s][tid];
        ksum[((size_t)((b * NHEAD + hh) * NCHUNK + c)) * DHEAD + tid] = s_;
    }
}

// ---------------- attention phase B: exclusive scan over chunks ------------
// grid B*NHEAD blocks, 1024 threads (one per (d,m) state element)
__global__ __launch_bounds__(1024) void attn_scan_kernel(
    const float* __restrict__ kvsum, const float* __restrict__ ksum,
    float* __restrict__ state, float* __restrict__ kstate) {
    int bh = blockIdx.x;
    int tid = threadIdx.x;
    size_t base = (size_t)bh * NCHUNK * (DHEAD * DHEAD);
    float vals[NCHUNK];
#pragma unroll
    for (int c = 0; c < NCHUNK; ++c)
        vals[c] = kvsum[base + (size_t)c * (DHEAD * DHEAD) + tid];
    float run = 0.f;
#pragma unroll
    for (int c = 0; c < NCHUNK; ++c) {
        float nv = vals[c];
        vals[c] = run;
        run += nv;
    }
#pragma unroll
    for (int c = 0; c < NCHUNK; ++c)
        state[base + (size_t)c * (DHEAD * DHEAD) + tid] = vals[c];
    if (tid < 32) {
        size_t kb = (size_t)bh * NCHUNK * DHEAD;
        float kv[NCHUNK];
#pragma unroll
        for (int c = 0; c < NCHUNK; ++c) kv[c] = ksum[kb + c * DHEAD + tid];
        float rk = 0.f;
#pragma unroll
        for (int c = 0; c < NCHUNK; ++c) {
            float nv = kv[c];
            kstate[kb + c * DHEAD + tid] = rk;
            rk += nv;
        }
    }
}

// ---------------- attention phase C: intra-chunk + state application -------
// grid (NCHUNK, NHEAD, B), 256 threads
__global__ __launch_bounds__(256) void attn_out_kernel(
    const float* __restrict__ q, const float* __restrict__ k,
    const float* __restrict__ v,
    const float* __restrict__ state, const float* __restrict__ kstate,
    float* __restrict__ out) {
    __shared__ float Qs[CHUNK][33];
    __shared__ float Ks[CHUNK][33];
    __shared__ float Vs[CHUNK][33];
    __shared__ float St[DHEAD][DHEAD];
    __shared__ float Aw[CHUNK][65];
    __shared__ float den[CHUNK];
    __shared__ float ksml[DHEAD];
    int c = blockIdx.x, hh = blockIdx.y, b = blockIdx.z;
    int tid = threadIdx.x;
    size_t base = ((size_t)(b * SEQ + c * CHUNK)) * DMODEL + hh * DHEAD;
#pragma unroll
    for (int i = 0; i < 8; ++i) {
        int s = (tid >> 5) + i * 8;
        int d = tid & 31;
        Qs[s][d] = phi(q[base + (size_t)s * DMODEL + d]);
        Ks[s][d] = phi(k[base + (size_t)s * DMODEL + d]);
        Vs[s][d] = v[base + (size_t)s * DMODEL + d];
    }
    size_t sb = ((size_t)((b * NHEAD + hh) * NCHUNK + c)) * (DHEAD * DHEAD);
#pragma unroll
    for (int i = 0; i < 4; ++i) {
        int idx = tid + i * 256;
        ((float*)St)[idx] = state[sb + idx];
    }
    if (tid < 32)
        ksml[tid] = kstate[((size_t)((b * NHEAD + hh) * NCHUNK + c)) * DHEAD + tid];
    __syncthreads();
    // scores A[s][t] = phi(Q_s) . phi(K_t) for t <= s
#pragma unroll
    for (int i = 0; i < 16; ++i) {
        int s_ = (tid >> 6) + 4 * i;
        int t_ = tid & 63;
        float a_ = 0.f;
        if (t_ <= s_) {
            for (int d = 0; d < DHEAD; ++d)
                a_ = fmaf(Qs[s_][d], Ks[t_][d], a_);
        }
        Aw[s_][t_] = a_;
    }
    __syncthreads();
    // denominators
    if (tid < CHUNK) {
        int s_ = tid;
        float d_ = 0.f;
        for (int d = 0; d < DHEAD; ++d) d_ = fmaf(Qs[s_][d], ksml[d], d_);
        for (int t_ = 0; t_ <= s_; ++t_) d_ += Aw[s_][t_];
        den[s_] = 1.f / (d_ + 1e-6f);
    }
    __syncthreads();
    // out[s][m] = (Q_s . St[:,m] + sum_{t<=s} A[s][t] V[t][m]) * den[s]
    int m = tid & 31;
#pragma unroll
    for (int i = 0; i < 8; ++i) {
        int s_ = (tid >> 5) * 8 + i;
        float o = 0.f;
        for (int d = 0; d < DHEAD; ++d) o = fmaf(Qs[s_][d], St[d][m], o);
        for (int t_ = 0; t_ <= s_; ++t_) o = fmaf(Aw[s_][t_], Vs[t_][m], o);
        out[base + (size_t)s_ * DMODEL + m] = o * den[s_];
    }
}

// ---------------------------------------------------------------------------
static inline void gemm(const float* A, const float* B, const float* bias,
                        float* C, int M, int N, int K, int relu,
                        hipStream_t s) {
    dim3 g(M / 64, N / 64);
    gemm_kernel<<<g, 256, 0, s>>>(A, B, bias, C, M, N, K, relu);
}

extern "C" void kernel_launch(void* const* d_in, const int* in_sizes, int n_in,
                              void* d_out, int out_size, void* d_ws, size_t ws_size,
                              hipStream_t stream) {
    const float* x      = (const float*)d_in[0];
    const float* g_in   = (const float*)d_in[1];
    const float* b_in   = (const float*)d_in[2];
    const float* W_pre  = (const float*)d_in[3];
    const float* b_pre  = (const float*)d_in[4];
    const float* Wq     = (const float*)d_in[5];
    const float* bq     = (const float*)d_in[6];
    const float* Wk     = (const float*)d_in[7];
    const float* bk     = (const float*)d_in[8];
    const float* Wv     = (const float*)d_in[9];
    const float* bv     = (const float*)d_in[10];
    const float* Wo     = (const float*)d_in[11];
    const float* bo     = (const float*)d_in[12];
    const float* W1     = (const float*)d_in[13];
    const float* bf1    = (const float*)d_in[14];
    const float* W2     = (const float*)d_in[15];
    const float* bf2    = (const float*)d_in[16];
    const float* ln1_g  = (const float*)d_in[17];
    const float* ln1_b  = (const float*)d_in[18];
    const float* ln2_g  = (const float*)d_in[19];
    const float* ln2_b  = (const float*)d_in[20];
    const float* lnf_g  = (const float*)d_in[21];
    const float* lnf_b  = (const float*)d_in[22];
    const float* W_post = (const float*)d_in[23];
    const float* b_post = (const float*)d_in[24];
    (void)in_sizes; (void)n_in; (void)out_size; (void)ws_size;

    float* ws = (float*)d_ws;
    const size_t SZ = (size_t)NROW * DMODEL;
    float* h      = ws;
    float* q      = h + SZ;
    float* k      = q + SZ;
    float* v      = k + SZ;
    float* t0     = v + SZ;
    float* t1     = t0 + SZ;
    float* xn     = t1 + SZ;            // 2048*240 fits in SZ
    float* kvsum  = xn + SZ;            // 32*16*1024 = 524288
    float* stat   = kvsum + 524288;
    float* ksum   = stat + 524288;      // 32*16*32 = 16384
    float* kstate = ksum + 16384;

    // input LN + pre-projection
    ln_kernel<<<NROW, 256, 0, stream>>>(x, nullptr, g_in, b_in, xn, FIN);
    gemm(xn, W_pre, b_pre, h, NROW, DMODEL, FIN, 0, stream);

    dim3 ag(NCHUNK, NHEAD, 2);
    const size_t WSZ = (size_t)DMODEL * DMODEL;
    for (int l = 0; l < NLAYER; ++l) {
        gemm(h, Wq + l * WSZ, bq + l * DMODEL, q, NROW, DMODEL, DMODEL, 0, stream);
        gemm(h, Wk + l * WSZ, bk + l * DMODEL, k, NROW, DMODEL, DMODEL, 0, stream);
        gemm(h, Wv + l * WSZ, bv + l * DMODEL, v, NROW, DMODEL, DMODEL, 0, stream);
        attn_sums_kernel<<<ag, 256, 0, stream>>>(k, v, kvsum, ksum);
        attn_scan_kernel<<<32, 1024, 0, stream>>>(kvsum, ksum, stat, kstate);
        attn_out_kernel<<<ag, 256, 0, stream>>>(q, k, v, stat, kstate, t0);
        gemm(t0, Wo + l * WSZ, bo + l * DMODEL, t1, NROW, DMODEL, DMODEL, 0, stream);
        ln_kernel<<<NROW, 256, 0, stream>>>(h, t1, ln1_g + l * DMODEL, ln1_b + l * DMODEL, h, DMODEL);
        gemm(h, W1 + l * WSZ, bf1 + l * DMODEL, t0, NROW, DMODEL, DMODEL, 1, stream);
        gemm(t0, W2 + l * WSZ, bf2 + l * DMODEL, t1, NROW, DMODEL, DMODEL, 0, stream);
        ln_kernel<<<NROW, 256, 0, stream>>>(h, t1, ln2_g + l * DMODEL, ln2_b + l * DMODEL, h, DMODEL);
    }

    // final LN + post projection
    ln_kernel<<<NROW, 256, 0, stream>>>(h, nullptr, lnf_g, lnf_b, t0, DMODEL);
    gemm(t0, W_post, b_post, (float*)d_out, NROW, DMODEL, DMODEL, 0, stream);
}

// Round 2
// 496.621 us; speedup vs baseline: 3.1213x; 3.1213x over previous
//
#include <hip/hip_runtime.h>
#include <hip/hip_bf16.h>
#include <cmath>

#define NROW 2048      // B*S
#define DMODEL 512
#define FIN 240
#define FINPAD 256
#define NHEAD 16
#define DHEAD 32
#define CHUNK 64
#define NCHUNK 16      // S / CHUNK
#define NLAYER 6
#define SEQ 1024
#define QKVLD 1536

typedef __attribute__((ext_vector_type(8))) short bf16x8;
typedef __attribute__((ext_vector_type(4))) float f32x4;

// phi(x) = elu(x) + 1
__device__ __forceinline__ float phi(float x) {
    return x > 0.f ? x + 1.f : expf(x);
}

__device__ __forceinline__ void load_lds16(const void* g, void* l) {
    __builtin_amdgcn_global_load_lds(
        (const __attribute__((address_space(1))) void*)g,
        (__attribute__((address_space(3))) void*)l, 16, 0, 0);
}

// ---------------- LayerNorm (optional residual add, fp32 and/or bf16 out) --
// one block per row, 256 threads; C <= 512, Cpad <= 512
__global__ __launch_bounds__(256) void ln_kernel(
    const float* __restrict__ in, const float* __restrict__ res,
    const float* __restrict__ g, const float* __restrict__ b,
    float* __restrict__ out, __hip_bfloat16* __restrict__ outb,
    int C, int Cpad) {
    int row = blockIdx.x;
    int tid = threadIdx.x;
    const float* xr = in + (size_t)row * C;
    const float* rr = res ? res + (size_t)row * C : nullptr;
    float vals[2];
    float sum = 0.f, sq = 0.f;
#pragma unroll
    for (int i = 0; i < 2; ++i) {
        int c = tid + i * 256;
        float v = 0.f;
        if (c < C) { v = xr[c]; if (rr) v += rr[c]; }
        vals[i] = v;
        sum += v; sq += v * v;
    }
#pragma unroll
    for (int off = 32; off > 0; off >>= 1) {
        sum += __shfl_xor(sum, off, 64);
        sq  += __shfl_xor(sq,  off, 64);
    }
    __shared__ float red[8];
    int wv = tid >> 6, ln = tid & 63;
    if (ln == 0) { red[wv] = sum; red[4 + wv] = sq; }
    __syncthreads();
    sum = red[0] + red[1] + red[2] + red[3];
    sq  = red[4] + red[5] + red[6] + red[7];
    float mean = sum / (float)C;
    float var  = sq / (float)C - mean * mean;
    float rstd = rsqrtf(var + 1e-5f);
#pragma unroll
    for (int i = 0; i < 2; ++i) {
        int c = tid + i * 256;
        float y = (vals[i] - mean) * rstd;
        if (c < C) {
            y = y * g[c] + b[c];
            if (out) out[(size_t)row * C + c] = y;
        }
        if (outb && c < Cpad)
            outb[(size_t)row * Cpad + c] = __float2bfloat16(c < C ? y : 0.f);
    }
}

// ---------------- bf16 MFMA GEMM: C = A[M,K] * Bt[N,K]^T + bias ------------
// BM=BN=64, BK=32, 256 threads (4 waves 2x2), each wave 32x32 = 2x2 frags
template<int RELU, int WF32, int WBF16>
__global__ __launch_bounds__(256) void gemm_bf16_kernel(
    const __hip_bfloat16* __restrict__ A, const __hip_bfloat16* __restrict__ Bt,
    const float* __restrict__ bias,
    float* __restrict__ C, __hip_bfloat16* __restrict__ Cb,
    int M, int N, int K) {
    __shared__ __align__(16) __hip_bfloat16 As[2][64][32];
    __shared__ __align__(16) __hip_bfloat16 Bs[2][64][32];
    int tid = threadIdx.x;
    int lane = tid & 63, w = tid >> 6;
    int bm = blockIdx.x * 64, bn = blockIdx.y * 64;
    // staging: wave w covers rows w*16..w*16+15; lane l -> row w*16+(l>>2), k (l&3)*8
    int srow = (w << 4) + (lane >> 2);
    int skk  = (lane & 3) << 3;
    const __hip_bfloat16* gaB = A  + (size_t)(bm + srow) * K + skk;
    const __hip_bfloat16* gbB = Bt + (size_t)(bn + srow) * K + skk;
    __hip_bfloat16* la0 = &As[0][w << 4][0];
    __hip_bfloat16* la1 = &As[1][w << 4][0];
    __hip_bfloat16* lb0 = &Bs[0][w << 4][0];
    __hip_bfloat16* lb1 = &Bs[1][w << 4][0];

    int wm = (w >> 1) << 5, wn = (w & 1) << 5;
    int fr = lane & 15, kg = (lane >> 4) << 3;
    f32x4 acc00 = {0.f, 0.f, 0.f, 0.f}, acc01 = acc00, acc10 = acc00, acc11 = acc00;

#define GSTAGE(k0, la, lb) do { load_lds16(gaB + (k0), la); load_lds16(gbB + (k0), lb); } while (0)
#define GCOMP(Asb, Bsb) do { \
        bf16x8 a0 = *(const bf16x8*)&Asb[wm + fr][kg]; \
        bf16x8 a1 = *(const bf16x8*)&Asb[wm + 16 + fr][kg]; \
        bf16x8 b0 = *(const bf16x8*)&Bsb[wn + fr][kg]; \
        bf16x8 b1 = *(const bf16x8*)&Bsb[wn + 16 + fr][kg]; \
        acc00 = __builtin_amdgcn_mfma_f32_16x16x32_bf16(a0, b0, acc00, 0, 0, 0); \
        acc01 = __builtin_amdgcn_mfma_f32_16x16x32_bf16(a0, b1, acc01, 0, 0, 0); \
        acc10 = __builtin_amdgcn_mfma_f32_16x16x32_bf16(a1, b0, acc10, 0, 0, 0); \
        acc11 = __builtin_amdgcn_mfma_f32_16x16x32_bf16(a1, b1, acc11, 0, 0, 0); \
    } while (0)

    GSTAGE(0, la0, lb0);
    __syncthreads();
    // K is a multiple of 64 (256 or 512): unroll by 2 for static buffer indices
    for (int k0 = 0; k0 < K; k0 += 64) {
        if (k0 + 32 < K) GSTAGE(k0 + 32, la1, lb1);
        GCOMP(As[0], Bs[0]);
        __syncthreads();
        if (k0 + 64 < K) GSTAGE(k0 + 64, la0, lb0);
        GCOMP(As[1], Bs[1]);
        __syncthreads();
    }
#undef GSTAGE
#undef GCOMP

    int fc = lane & 15, frr = (lane >> 4) << 2;
    float acc[2][2][4];
#pragma unroll
    for (int r = 0; r < 4; ++r) {
        acc[0][0][r] = acc00[r]; acc[0][1][r] = acc01[r];
        acc[1][0][r] = acc10[r]; acc[1][1][r] = acc11[r];
    }
#pragma unroll
    for (int i = 0; i < 2; ++i)
#pragma unroll
        for (int j = 0; j < 2; ++j) {
            int col = bn + wn + j * 16 + fc;
            float bsv = bias[col];
#pragma unroll
            for (int r = 0; r < 4; ++r) {
                int row = bm + wm + i * 16 + frr + r;
                float v = acc[i][j][r] + bsv;
                if (RELU) v = fmaxf(v, 0.f);
                if (WF32)  C[(size_t)row * N + col] = v;
                if (WBF16) Cb[(size_t)row * N + col] = __float2bfloat16(v);
            }
        }
}

// ---------------- weight transpose + bf16 convert ---------------------------
// src fp32 [K][512] -> dst bf16 [512][Kpad] (zero-padded k>=K); 64x64 tiles
__global__ __launch_bounds__(256) void wconv_kernel(
    const float* __restrict__ W_pre, const float* __restrict__ Wq,
    const float* __restrict__ Wk, const float* __restrict__ Wv,
    const float* __restrict__ Wo, const float* __restrict__ W1,
    const float* __restrict__ W2, const float* __restrict__ W_post,
    __hip_bfloat16* wpre_t, __hip_bfloat16* wqkv_t, __hip_bfloat16* wo_t,
    __hip_bfloat16* w1_t, __hip_bfloat16* w2_t, __hip_bfloat16* wpost_t) {
    __shared__ float tile[64][65];
    int tb = blockIdx.x;
    const float* src; __hip_bfloat16* dst; int K, Kpad, kt, nt;
    if (tb < 32) {
        src = W_pre; dst = wpre_t; K = FIN; Kpad = FINPAD;
        kt = tb >> 3; nt = tb & 7;
    } else {
        int t2 = tb - 32; int mat = t2 >> 6; int tt = t2 & 63;
        kt = tt >> 3; nt = tt & 7; K = 512; Kpad = 512;
        if (mat == 36) { src = W_post; dst = wpost_t; }
        else {
            int l = mat / 6, j = mat % 6;
            const size_t WSZ = 262144;
            switch (j) {
                case 0: src = Wq + l * WSZ; dst = wqkv_t + l * 786432;          break;
                case 1: src = Wk + l * WSZ; dst = wqkv_t + l * 786432 + 262144; break;
                case 2: src = Wv + l * WSZ; dst = wqkv_t + l * 786432 + 524288; break;
                case 3: src = Wo + l * WSZ; dst = wo_t + l * WSZ;               break;
                case 4: src = W1 + l * WSZ; dst = w1_t + l * WSZ;               break;
                default: src = W2 + l * WSZ; dst = w2_t + l * WSZ;              break;
            }
        }
    }
    const int N = 512;
    int t = threadIdx.x;
    int k0 = kt * 64, n0 = nt * 64;
#pragma unroll
    for (int i = 0; i < 16; ++i) {
        int kk = (t >> 6) * 16 + i;
        int nn = t & 63;
        int k = k0 + kk;
        tile[kk][nn] = (k < K) ? src[(size_t)k * N + n0 + nn] : 0.f;
    }
    __syncthreads();
#pragma unroll
    for (int i = 0; i < 16; ++i) {
        int nn = (t >> 6) * 16 + i;
        int kk = t & 63;
        dst[(size_t)(n0 + nn) * Kpad + k0 + kk] = __float2bfloat16(tile[kk][nn]);
    }
}

__global__ void bias_concat_kernel(const float* __restrict__ bq,
                                   const float* __restrict__ bk,
                                   const float* __restrict__ bv,
                                   float* __restrict__ o) {
    int l = blockIdx.x, t = threadIdx.x;  // 512 threads
    o[l * QKVLD + t]        = bq[l * DMODEL + t];
    o[l * QKVLD + 512 + t]  = bk[l * DMODEL + t];
    o[l * QKVLD + 1024 + t] = bv[l * DMODEL + t];
}

// ---------------- attention phase A: per-chunk K^T V sums + K column sums --
// grid (NCHUNK, NHEAD, B), 256 threads; k,v row stride ld
__global__ __launch_bounds__(256) void attn_sums_kernel(
    const float* __restrict__ k, const float* __restrict__ v, int ld,
    float* __restrict__ kvsum, float* __restrict__ ksum) {
    __shared__ float Ks[CHUNK][33];
    __shared__ float Vs[CHUNK][33];
    int c = blockIdx.x, hh = blockIdx.y, b = blockIdx.z;
    int tid = threadIdx.x;
    size_t base = ((size_t)(b * SEQ + c * CHUNK)) * ld + hh * DHEAD;
#pragma unroll
    for (int i = 0; i < 8; ++i) {
        int s = (tid >> 5) + i * 8;
        int d = tid & 31;
        Ks[s][d] = phi(k[base + (size_t)s * ld + d]);
        Vs[s][d] = v[base + (size_t)s * ld + d];
    }
    __syncthreads();
    int m = tid & 31;
    float acc[4] = {0.f, 0.f, 0.f, 0.f};
    for (int s = 0; s < CHUNK; ++s) {
        float vm = Vs[s][m];
#pragma unroll
        for (int i = 0; i < 4; ++i)
            acc[i] = fmaf(Ks[s][(tid >> 5) + 8 * i], vm, acc[i]);
    }
    size_t ob = ((size_t)((b * NHEAD + hh) * NCHUNK + c)) * (DHEAD * DHEAD);
#pragma unroll
    for (int i = 0; i < 4; ++i)
        kvsum[ob + (size_t)((tid >> 5) + 8 * i) * DHEAD + m] = acc[i];
    if (tid < 32) {
        float s_ = 0.f;
        for (int s = 0; s < CHUNK; ++s) s_ += Ks[s][tid];
        ksum[((size_t)((b * NHEAD + hh) * NCHUNK + c)) * DHEAD + tid] = s_;
    }
}

// ---------------- attention phase B: exclusive scan over chunks ------------
__global__ __launch_bounds__(1024) void attn_scan_kernel(
    const float* __restrict__ kvsum, const float* __restrict__ ksum,
    float* __restrict__ state, float* __restrict__ kstate) {
    int bh = blockIdx.x;
    int tid = threadIdx.x;
    size_t base = (size_t)bh * NCHUNK * (DHEAD * DHEAD);
    float vals[NCHUNK];
#pragma unroll
    for (int c = 0; c < NCHUNK; ++c)
        vals[c] = kvsum[base + (size_t)c * (DHEAD * DHEAD) + tid];
    float run = 0.f;
#pragma unroll
    for (int c = 0; c < NCHUNK; ++c) {
        float nv = vals[c];
        vals[c] = run;
        run += nv;
    }
#pragma unroll
    for (int c = 0; c < NCHUNK; ++c)
        state[base + (size_t)c * (DHEAD * DHEAD) + tid] = vals[c];
    if (tid < 32) {
        size_t kb = (size_t)bh * NCHUNK * DHEAD;
        float kv[NCHUNK];
#pragma unroll
        for (int c = 0; c < NCHUNK; ++c) kv[c] = ksum[kb + c * DHEAD + tid];
        float rk = 0.f;
#pragma unroll
        for (int c = 0; c < NCHUNK; ++c) {
            float nv = kv[c];
            kstate[kb + c * DHEAD + tid] = rk;
            rk += nv;
        }
    }
}

// ---------------- attention phase C: intra-chunk + state application -------
// grid (NCHUNK, NHEAD, B), 256 threads; q,k,v row stride ld; out bf16 stride 512
__global__ __launch_bounds__(256) void attn_out_kernel(
    const float* __restrict__ q, const float* __restrict__ k,
    const float* __restrict__ v, int ld,
    const float* __restrict__ state, const float* __restrict__ kstate,
    __hip_bfloat16* __restrict__ out) {
    __shared__ float Qs[CHUNK][33];
    __shared__ float Ks[CHUNK][33];
    __shared__ float Vs[CHUNK][33];
    __shared__ float St[DHEAD][DHEAD];
    __shared__ float Aw[CHUNK][65];
    __shared__ float den[CHUNK];
    __shared__ float ksml[DHEAD];
    int c = blockIdx.x, hh = blockIdx.y, b = blockIdx.z;
    int tid = threadIdx.x;
    size_t base = ((size_t)(b * SEQ + c * CHUNK)) * ld + hh * DHEAD;
#pragma unroll
    for (int i = 0; i < 8; ++i) {
        int s = (tid >> 5) + i * 8;
        int d = tid & 31;
        Qs[s][d] = phi(q[base + (size_t)s * ld + d]);
        Ks[s][d] = phi(k[base + (size_t)s * ld + d]);
        Vs[s][d] = v[base + (size_t)s * ld + d];
    }
    size_t sb = ((size_t)((b * NHEAD + hh) * NCHUNK + c)) * (DHEAD * DHEAD);
#pragma unroll
    for (int i = 0; i < 4; ++i) {
        int idx = tid + i * 256;
        ((float*)St)[idx] = state[sb + idx];
    }
    if (tid < 32)
        ksml[tid] = kstate[((size_t)((b * NHEAD + hh) * NCHUNK + c)) * DHEAD + tid];
    __syncthreads();
#pragma unroll
    for (int i = 0; i < 16; ++i) {
        int s_ = (tid >> 6) + 4 * i;
        int t_ = tid & 63;
        float a_ = 0.f;
        if (t_ <= s_) {
            for (int d = 0; d < DHEAD; ++d)
                a_ = fmaf(Qs[s_][d], Ks[t_][d], a_);
        }
        Aw[s_][t_] = a_;
    }
    __syncthreads();
    if (tid < CHUNK) {
        int s_ = tid;
        float d_ = 0.f;
        for (int d = 0; d < DHEAD; ++d) d_ = fmaf(Qs[s_][d], ksml[d], d_);
        for (int t_ = 0; t_ <= s_; ++t_) d_ += Aw[s_][t_];
        den[s_] = 1.f / (d_ + 1e-6f);
    }
    __syncthreads();
    int m = tid & 31;
    size_t obase = ((size_t)(b * SEQ + c * CHUNK)) * DMODEL + hh * DHEAD;
#pragma unroll
    for (int i = 0; i < 8; ++i) {
        int s_ = (tid >> 5) * 8 + i;
        float o = 0.f;
        for (int d = 0; d < DHEAD; ++d) o = fmaf(Qs[s_][d], St[d][m], o);
        for (int t_ = 0; t_ <= s_; ++t_) o = fmaf(Aw[s_][t_], Vs[t_][m], o);
        out[obase + (size_t)s_ * DMODEL + m] = __float2bfloat16(o * den[s_]);
    }
}

// ---------------------------------------------------------------------------
template<int R, int WF, int WB>
static inline void gemm(const __hip_bfloat16* A, const __hip_bfloat16* Bt,
                        const float* bias, float* C, __hip_bfloat16* Cb,
                        int M, int N, int K, hipStream_t s) {
    dim3 g(M / 64, N / 64);
    gemm_bf16_kernel<R, WF, WB><<<g, 256, 0, s>>>(A, Bt, bias, C, Cb, M, N, K);
}

extern "C" void kernel_launch(void* const* d_in, const int* in_sizes, int n_in,
                              void* d_out, int out_size, void* d_ws, size_t ws_size,
                              hipStream_t stream) {
    const float* x      = (const float*)d_in[0];
    const float* g_in   = (const float*)d_in[1];
    const float* b_in   = (const float*)d_in[2];
    const float* W_pre  = (const float*)d_in[3];
    const float* b_pre  = (const float*)d_in[4];
    const float* Wq     = (const float*)d_in[5];
    const float* bq     = (const float*)d_in[6];
    const float* Wk     = (const float*)d_in[7];
    const float* bk     = (const float*)d_in[8];
    const float* Wv     = (const float*)d_in[9];
    const float* bv     = (const float*)d_in[10];
    const float* Wo     = (const float*)d_in[11];
    const float* bo     = (const float*)d_in[12];
    const float* W1     = (const float*)d_in[13];
    const float* bf1    = (const float*)d_in[14];
    const float* W2     = (const float*)d_in[15];
    const float* bf2    = (const float*)d_in[16];
    const float* ln1_g  = (const float*)d_in[17];
    const float* ln1_b  = (const float*)d_in[18];
    const float* ln2_g  = (const float*)d_in[19];
    const float* ln2_b  = (const float*)d_in[20];
    const float* lnf_g  = (const float*)d_in[21];
    const float* lnf_b  = (const float*)d_in[22];
    const float* W_post = (const float*)d_in[23];
    const float* b_post = (const float*)d_in[24];
    (void)in_sizes; (void)n_in; (void)out_size; (void)ws_size;

    float* ws = (float*)d_ws;
    const size_t SZ = (size_t)NROW * DMODEL;          // 1048576
    float* h       = ws;
    float* qkv     = h + SZ;                          // 2048*1536 = 3145728
    float* t1      = qkv + 3145728;
    float* kvsum   = t1 + SZ;                         // 524288
    float* stat    = kvsum + 524288;
    float* ksum    = stat + 524288;                   // 16384
    float* kstate  = ksum + 16384;
    float* qkvbias = kstate + 16384;                  // 6*1536 = 9216
    __hip_bfloat16* bp = (__hip_bfloat16*)(qkvbias + 9216);
    __hip_bfloat16* hb     = bp;            bp += SZ;
    __hip_bfloat16* xnb    = bp;            bp += (size_t)NROW * FINPAD;   // 524288
    __hip_bfloat16* attb   = bp;            bp += SZ;
    __hip_bfloat16* ffb    = bp;            bp += SZ;
    __hip_bfloat16* t0b    = bp;            bp += SZ;
    __hip_bfloat16* wpre_t = bp;            bp += (size_t)DMODEL * FINPAD; // 131072
    __hip_bfloat16* wqkv_t = bp;            bp += (size_t)NLAYER * 786432;
    __hip_bfloat16* wo_t   = bp;            bp += (size_t)NLAYER * 262144;
    __hip_bfloat16* w1_t   = bp;            bp += (size_t)NLAYER * 262144;
    __hip_bfloat16* w2_t   = bp;            bp += (size_t)NLAYER * 262144;
    __hip_bfloat16* wpost_t= bp;

    // one-time-per-call weight conversion (graph-safe, deterministic)
    wconv_kernel<<<32 + 37 * 64, 256, 0, stream>>>(
        W_pre, Wq, Wk, Wv, Wo, W1, W2, W_post,
        wpre_t, wqkv_t, wo_t, w1_t, w2_t, wpost_t);
    bias_concat_kernel<<<NLAYER, 512, 0, stream>>>(bq, bk, bv, qkvbias);

    // input LN (bf16, K padded 240->256) + pre projection (h fp32 + hb bf16)
    ln_kernel<<<NROW, 256, 0, stream>>>(x, nullptr, g_in, b_in, nullptr, xnb, FIN, FINPAD);
    gemm<0, 1, 1>(xnb, wpre_t, b_pre, h, hb, NROW, DMODEL, FINPAD, stream);

    dim3 ag(NCHUNK, NHEAD, 2);
    for (int l = 0; l < NLAYER; ++l) {
        // fused QKV projection -> qkv fp32 [2048][1536]
        gemm<0, 1, 0>(hb, wqkv_t + (size_t)l * 786432, qkvbias + l * QKVLD,
                      qkv, nullptr, NROW, QKVLD, DMODEL, stream);
        const float* qp = qkv;
        const float* kp = qkv + 512;
        const float* vp = qkv + 1024;
        attn_sums_kernel<<<ag, 256, 0, stream>>>(kp, vp, QKVLD, kvsum, ksum);
        attn_scan_kernel<<<32, 1024, 0, stream>>>(kvsum, ksum, stat, kstate);
        attn_out_kernel<<<ag, 256, 0, stream>>>(qp, kp, vp, QKVLD, stat, kstate, attb);
        gemm<0, 1, 0>(attb, wo_t + (size_t)l * 262144, bo + l * DMODEL,
                      t1, nullptr, NROW, DMODEL, DMODEL, stream);
        ln_kernel<<<NROW, 256, 0, stream>>>(h, t1, ln1_g + l * DMODEL, ln1_b + l * DMODEL,
                                            h, hb, DMODEL, DMODEL);
        gemm<1, 0, 1>(hb, w1_t + (size_t)l * 262144, bf1 + l * DMODEL,
                      nullptr, ffb, NROW, DMODEL, DMODEL, stream);
        gemm<0, 1, 0>(ffb, w2_t + (size_t)l * 262144, bf2 + l * DMODEL,
                      t1, nullptr, NROW, DMODEL, DMODEL, stream);
        ln_kernel<<<NROW, 256, 0, stream>>>(h, t1, ln2_g + l * DMODEL, ln2_b + l * DMODEL,
                                            h, hb, DMODEL, DMODEL);
    }

    // final LN (bf16 only) + post projection (fp32 to d_out)
    ln_kernel<<<NROW, 256, 0, stream>>>(h, nullptr, lnf_g, lnf_b, nullptr, t0b, DMODEL, DMODEL);
    gemm<0, 1, 0>(t0b, wpost_t, b_post, (float*)d_out, nullptr, NROW, DMODEL, DMODEL, stream);
}